// Round 6
// baseline (459.480 us; speedup 1.0000x reference)
//
#include <hip/hip_runtime.h>
#include <hip/hip_bf16.h>

typedef __bf16 bf16_t;
typedef __bf16 bf16x8 __attribute__((ext_vector_type(8)));
typedef float f32x4 __attribute__((ext_vector_type(4)));
typedef float f32x8 __attribute__((ext_vector_type(8)));
typedef float f32x16 __attribute__((ext_vector_type(16)));
typedef unsigned int u32;

#define GAS __attribute__((address_space(1)))
#define LAS __attribute__((address_space(3)))

#define B_N 32
#define T_N 2048
#define C_N 256
#define F_N 1024
#define NSPLIT 16
#define TSUB 128
#define NCHUNK 32
#define CHBYTES 32768

// inline-asm pieces: all-asm GEMM2 pipeline (order guaranteed among asm volatile)
#define DSR(dst, addr, IMM) \
  asm volatile("ds_read_b128 %0, %1 offset:" IMM : "=v"(dst) : "v"(addr))
#define LGK(N) asm volatile("s_waitcnt lgkmcnt(" N ")")
#define MFA(acc, A, B) \
  asm volatile("v_mfma_f32_32x32x16_bf16 %0, %1, %2, %0" : "+a"(acc) : "v"(A), "v"(B))

// ---------------- weight prep: build LDS-image layouts in ws ----------------
// W1 image per chunk ch (32 hidden rows): entry (kg 0..31, hl 0..31) 16B =
//   { bf16(W1[kg*8+j][ch*32+hl]) j=0..7 }  at  ch*32768 + kg*512 + hl*16
// W2 image per chunk: entry (G 0..3, cc 0..255) 16B at ch*32768 + 16384 + G*4096 + cc*16
//   element e = bf16(W2[ch*32 + perm(G,e)][cc]),  perm = (e&3) + 8*(2*(G>>1)+(e>>2)) + 4*(G&1)
__global__ __launch_bounds__(256) void k_prep(
    const float* __restrict__ W1, const float* __restrict__ W2,
    bf16_t* __restrict__ wsW) {
  int id = blockIdx.x * 256 + threadIdx.x;
  char* wb = (char*)wsW;
  if (id < 32768) {
    const int kg = id >> 10, h = id & 1023;
    const int ch = h >> 5, hl = h & 31;
    const float* src = W1 + (size_t)(kg << 3) * F_N + h;
    bf16x8 v;
#pragma unroll
    for (int j = 0; j < 8; ++j) v[j] = (bf16_t)src[(size_t)j * F_N];
    *(bf16x8*)(wb + (size_t)ch * CHBYTES + (kg << 9) + (hl << 4)) = v;
  } else {
    id -= 32768;
    const int Hg = id >> 8, cc = id & 255;
    const int ch = Hg >> 2, G = Hg & 3;
    bf16x8 v;
#pragma unroll
    for (int e = 0; e < 8; ++e) {
      const int hid = (ch << 5) + (e & 3) + ((((G >> 1) << 1) + (e >> 2)) << 3) + ((G & 1) << 2);
      v[e] = (bf16_t)W2[(size_t)hid * C_N + cc];
    }
    *(bf16x8*)(wb + (size_t)ch * CHBYTES + 16384 + (G << 12) + (cc << 4)) = v;
  }
}

// ---------------- stats pass 1: partial sum / sumsq over a T-slice ----------------
__global__ __launch_bounds__(256) void k_stats_partial(
    const float* __restrict__ x, float* __restrict__ psum, float* __restrict__ psq) {
  const int blk = blockIdx.x;
  const int b = blk / NSPLIT, s = blk % NSPLIT;
  const int tid = threadIdx.x;
  const int c4 = (tid & 63) << 2;
  const int tg = tid >> 6;
  const float* xb = x + ((size_t)b * T_N + (size_t)s * TSUB) * C_N;
  f32x4 sum = {0.f, 0.f, 0.f, 0.f};
  f32x4 sq  = {0.f, 0.f, 0.f, 0.f};
#pragma unroll 4
  for (int i = 0; i < TSUB / 4; ++i) {
    const int t = tg + (i << 2);
    f32x4 v = *(const f32x4*)(xb + (size_t)t * C_N + c4);
    sum += v;
    sq += v * v;
  }
  __shared__ f32x4 ls[256];
  __shared__ f32x4 lq[256];
  ls[tid] = sum; lq[tid] = sq;
  __syncthreads();
  if (tid < 64) {
    f32x4 S = ls[tid] + ls[tid + 64] + ls[tid + 128] + ls[tid + 192];
    f32x4 Q = lq[tid] + lq[tid + 64] + lq[tid + 128] + lq[tid + 192];
    *(f32x4*)(psum + (size_t)blk * C_N + c4) = S;
    *(f32x4*)(psq  + (size_t)blk * C_N + c4) = Q;
  }
}

// ---------------- stats pass 2: fused scale/shift (ddof=1) ----------------
__global__ __launch_bounds__(256) void k_stats_final(
    const float* __restrict__ psum, const float* __restrict__ psq,
    const float* __restrict__ gamma, const float* __restrict__ beta,
    float* __restrict__ As, float* __restrict__ Bs) {
  const int b = blockIdx.x, c = threadIdx.x;
  float S = 0.f, Q = 0.f;
#pragma unroll
  for (int s = 0; s < NSPLIT; ++s) {
    S += psum[(size_t)(b * NSPLIT + s) * C_N + c];
    Q += psq[(size_t)(b * NSPLIT + s) * C_N + c];
  }
  const float mu = S / (float)T_N;
  const float var = (Q - (float)T_N * mu * mu) / (float)(T_N - 1);
  const float a = rsqrtf(var + 1e-5f) * gamma[c];
  As[b * C_N + c] = a;
  Bs[b * C_N + c] = beta[c] - mu * a;
}

// ---------------- fused FFN: 64 tokens/wave, h in regs, GEMM2 all-asm into AGPRs ----------------
__global__ __launch_bounds__(256, 1) void k_ffn(
    const float* __restrict__ x, const float* __restrict__ As,
    const float* __restrict__ Bs, const float* __restrict__ b1,
    const float* __restrict__ b2, const bf16_t* __restrict__ wsW,
    float* __restrict__ out) {
  __shared__ __attribute__((aligned(128))) unsigned char lds[2 * CHBYTES];

  const int tid = threadIdx.x;
  const int lane = tid & 63;
  const int w = tid >> 6;
  const int l31 = lane & 31;
  const int g = lane >> 5;

  const int tok0 = blockIdx.x << 8;       // 256 tokens / block
  const int b = blockIdx.x >> 3;          // 8 blocks per batch row
  const int t0 = tok0 + (w << 6);         // this wave's 64 tokens (2 tiles of 32)

  const char* wsb = (const char*)wsW;

  // stage chunk 0 into buffer 0
#pragma unroll
  for (int j = 0; j < 8; ++j) {
    const int off = (j << 12) + (tid << 4);
    __builtin_amdgcn_global_load_lds((const GAS u32*)(wsb + off),
                                     (LAS u32*)(&lds[off]), 16, 0, 0);
  }

  // prologue: normalized h fragments for both token tiles (128 VGPR)
  bf16x8 hfrag[2][16];
  {
    const float* ar = As + b * C_N;
    const float* br = Bs + b * C_N;
#pragma unroll
    for (int ti = 0; ti < 2; ++ti) {
      const float* xrow = x + (size_t)(t0 + (ti << 5) + l31) * C_N;
#pragma unroll
      for (int ks = 0; ks < 16; ++ks) {
        const int c0 = (ks << 4) + (g << 3);
        f32x8 xv = *(const f32x8*)(xrow + c0);
        f32x8 av = *(const f32x8*)(ar + c0);
        f32x8 bv = *(const f32x8*)(br + c0);
        f32x8 hv = xv * av + bv;
#pragma unroll
        for (int e = 0; e < 8; ++e) hfrag[ti][ks][e] = (bf16_t)hv[e];
      }
    }
  }

  f32x16 accO0[8], accO1[8];
#pragma unroll
  for (int nb = 0; nb < 8; ++nb)
#pragma unroll
    for (int e = 0; e < 16; ++e) { accO0[nb][e] = 0.f; accO1[nb][e] = 0.f; }

  __syncthreads();   // chunk-0 stage complete

#pragma unroll 1
  for (int ch = 0; ch < NCHUNK; ++ch) {
    // stage next chunk into the other buffer (VMEM only; drained by syncthreads)
    if (ch + 1 < NCHUNK) {
      const char* gsrc = wsb + (size_t)(ch + 1) * CHBYTES;
      unsigned char* ldst = &lds[((ch + 1) & 1) * CHBYTES];
#pragma unroll
      for (int j = 0; j < 8; ++j) {
        const int off = (j << 12) + (tid << 4);
        __builtin_amdgcn_global_load_lds((const GAS u32*)(gsrc + off),
                                         (LAS u32*)(ldst + off), 16, 0, 0);
      }
    }
    const unsigned char* W1c = &lds[(ch & 1) * CHBYTES];

    // GEMM1 (swapped, compiler-scheduled): D1[hid][token], one wf read feeds both tiles.
    // Two independent chains (a/b alternate) -> dep distance 2.
    f32x16 D1a, D1b;
#pragma unroll
    for (int e = 0; e < 16; ++e) { D1a[e] = 0.f; D1b[e] = 0.f; }
#pragma unroll
    for (int ks = 0; ks < 16; ++ks) {
      const bf16x8 wf = *(const bf16x8*)(W1c + ((((ks << 1) + g) << 9) + (l31 << 4)));
      D1a = __builtin_amdgcn_mfma_f32_32x32x16_bf16(wf, hfrag[0][ks], D1a, 0, 0, 0);
      D1b = __builtin_amdgcn_mfma_f32_32x32x16_bf16(wf, hfrag[1][ks], D1b, 0, 0, 0);
    }

    // bias (from global, L1-hot; keeps lgkmcnt exact for the asm region)
    const float* b1c = b1 + (ch << 5) + (g << 2);
    const f32x4 b1q0 = *(const f32x4*)(b1c);
    const f32x4 b1q1 = *(const f32x4*)(b1c + 8);
    const f32x4 b1q2 = *(const f32x4*)(b1c + 16);
    const f32x4 b1q3 = *(const f32x4*)(b1c + 24);

    // ReLU + cast: reg r holds hid = (r&3)+8*(r>>2)+4g
    bf16x8 af0, af1, af0b, af1b;
#pragma unroll
    for (int r = 0; r < 16; ++r) {
      const float bb = (r < 4 ? b1q0 : r < 8 ? b1q1 : r < 12 ? b1q2 : b1q3)[r & 3];
      float v0 = D1a[r] + bb;
      float v1 = D1b[r] + bb;
      v0 = v0 > 0.f ? v0 : 0.f;
      v1 = v1 > 0.f ? v1 : 0.f;
      if (r < 8) { af0[r] = (bf16_t)v0; af1[r] = (bf16_t)v1; }
      else       { af0b[r - 8] = (bf16_t)v0; af1b[r - 8] = (bf16_t)v1; }
    }

    // ---- GEMM2: all-asm, 6-slot depth-3 pipelined ds_read + MFMA into AGPRs ----
    const unsigned w2a = (unsigned)(size_t)(W1c + 16384) + (g << 12) + (l31 << 4);

    asm volatile("s_waitcnt lgkmcnt(0)" ::: "memory");  // GEMM1 ds ops fully retired
    __builtin_amdgcn_sched_barrier(0);                  // nothing crosses into asm region
    asm volatile("s_nop 1");                            // VALU(af) -> MFMA spacing

    {
      bf16x8 s0, s1, s2, s3, s4, s5;
      DSR(s0, w2a, "0"); DSR(s1, w2a, "512"); DSR(s2, w2a, "1024");
      DSR(s3, w2a, "1536");  LGK("3"); MFA(accO0[0], af0,  s0); MFA(accO1[0], af1,  s0);
      DSR(s4, w2a, "2048");  LGK("3"); MFA(accO0[1], af0,  s1); MFA(accO1[1], af1,  s1);
      DSR(s5, w2a, "2560");  LGK("3"); MFA(accO0[2], af0,  s2); MFA(accO1[2], af1,  s2);
      DSR(s0, w2a, "3072");  LGK("3"); MFA(accO0[3], af0,  s3); MFA(accO1[3], af1,  s3);
      DSR(s1, w2a, "3584");  LGK("3"); MFA(accO0[4], af0,  s4); MFA(accO1[4], af1,  s4);
      DSR(s2, w2a, "8192");  LGK("3"); MFA(accO0[5], af0,  s5); MFA(accO1[5], af1,  s5);
      DSR(s3, w2a, "8704");  LGK("3"); MFA(accO0[6], af0,  s0); MFA(accO1[6], af1,  s0);
      DSR(s4, w2a, "9216");  LGK("3"); MFA(accO0[7], af0,  s1); MFA(accO1[7], af1,  s1);
      DSR(s5, w2a, "9728");  LGK("3"); MFA(accO0[0], af0b, s2); MFA(accO1[0], af1b, s2);
      DSR(s0, w2a, "10240"); LGK("3"); MFA(accO0[1], af0b, s3); MFA(accO1[1], af1b, s3);
      DSR(s1, w2a, "10752"); LGK("3"); MFA(accO0[2], af0b, s4); MFA(accO1[2], af1b, s4);
      DSR(s2, w2a, "11264"); LGK("3"); MFA(accO0[3], af0b, s5); MFA(accO1[3], af1b, s5);
      DSR(s3, w2a, "11776"); LGK("3"); MFA(accO0[4], af0b, s0); MFA(accO1[4], af1b, s0);
                             LGK("2"); MFA(accO0[5], af0b, s1); MFA(accO1[5], af1b, s1);
                             LGK("1"); MFA(accO0[6], af0b, s2); MFA(accO1[6], af1b, s2);
                             LGK("0"); MFA(accO0[7], af0b, s3); MFA(accO1[7], af1b, s3);
    }
    __builtin_amdgcn_sched_barrier(0);

    __syncthreads();   // drains stage vmcnt + separates buffer reuse
  }

  // asm MFMA (AGPR write) -> VALU/accvgpr_read hazard spacing (compiler can't model)
  asm volatile("s_nop 7\ns_nop 7\ns_nop 2");

  // epilogue: out = accO + b2 + x   (token = t0 + ti*32 + 4g + rr + 8q, col = nb*32 + l31)
#pragma unroll
  for (int ti = 0; ti < 2; ++ti) {
    const float* xbase = x + (size_t)(t0 + (ti << 5) + (g << 2)) * C_N;
    float* obase = out + (size_t)(t0 + (ti << 5) + (g << 2)) * C_N;
#pragma unroll
    for (int nb = 0; nb < 8; ++nb) {
      const int c = (nb << 5) + l31;
      const float b2v = b2[c];
#pragma unroll
      for (int q = 0; q < 4; ++q) {
#pragma unroll
        for (int rr = 0; rr < 4; ++rr) {
          const size_t idx = (size_t)((q << 3) + rr) * C_N + c;
          const f32x16& a = ti ? accO1[nb] : accO0[nb];
          obase[idx] = a[(q << 2) + rr] + b2v + xbase[idx];
        }
      }
    }
  }
}

extern "C" void kernel_launch(void* const* d_in, const int* in_sizes, int n_in,
                              void* d_out, int out_size, void* d_ws, size_t ws_size,
                              hipStream_t stream) {
  const float* x     = (const float*)d_in[0];
  const float* gamma = (const float*)d_in[1];
  const float* beta  = (const float*)d_in[2];
  const float* W1    = (const float*)d_in[3];
  const float* b1    = (const float*)d_in[4];
  const float* W2    = (const float*)d_in[5];
  const float* b2    = (const float*)d_in[6];
  float* out = (float*)d_out;

  char* ws = (char*)d_ws;
  bf16_t* wsW  = (bf16_t*)ws;                           // 1 MB
  float* psum  = (float*)(ws + (1024 << 10));           // 512 KB
  float* psq   = (float*)(ws + (1536 << 10));           // 512 KB
  float* As    = (float*)(ws + (2048 << 10));           // 32 KB
  float* Bs    = (float*)(ws + (2048 << 10) + (32 << 10));

  k_prep<<<256, 256, 0, stream>>>(W1, W2, wsW);
  k_stats_partial<<<B_N * NSPLIT, 256, 0, stream>>>(x, psum, psq);
  k_stats_final<<<B_N, 256, 0, stream>>>(psum, psq, gamma, beta, As, Bs);
  k_ffn<<<256, 256, 0, stream>>>(x, As, Bs, b1, b2, wsW, out);
}

// Round 7
// 105.788 us; speedup vs baseline: 4.3434x; 4.3434x over previous
//
#include <hip/hip_runtime.h>
#include <hip/hip_bf16.h>

typedef __bf16 bf16_t;
typedef __bf16 bf16x8 __attribute__((ext_vector_type(8)));
typedef float f32x4 __attribute__((ext_vector_type(4)));
typedef float f32x8 __attribute__((ext_vector_type(8)));
typedef float f32x16 __attribute__((ext_vector_type(16)));
typedef unsigned int u32;

#define GAS __attribute__((address_space(1)))
#define LAS __attribute__((address_space(3)))

#define B_N 32
#define T_N 2048
#define C_N 256
#define F_N 1024
#define NSPLIT 16
#define TSUB 128
#define NCHUNK 32
#define CHBYTES 32768

// ---------------- weight prep: build LDS-image layouts in ws ----------------
// W1 image per chunk ch (32 hidden rows): entry (kg 0..31, hl 0..31) 16B =
//   { bf16(W1[kg*8+j][ch*32+hl]) j=0..7 }  at  ch*32768 + kg*512 + hl*16
// W2 image per chunk: entry (G 0..3, cc 0..255) 16B at ch*32768 + 16384 + G*4096 + cc*16
//   element e = bf16(W2[ch*32 + perm(G,e)][cc]),  perm = (e&3) + 8*(2*(G>>1)+(e>>2)) + 4*(G&1)
__global__ __launch_bounds__(256) void k_prep(
    const float* __restrict__ W1, const float* __restrict__ W2,
    bf16_t* __restrict__ wsW) {
  int id = blockIdx.x * 256 + threadIdx.x;
  char* wb = (char*)wsW;
  if (id < 32768) {
    const int kg = id >> 10, h = id & 1023;
    const int ch = h >> 5, hl = h & 31;
    const float* src = W1 + (size_t)(kg << 3) * F_N + h;
    bf16x8 v;
#pragma unroll
    for (int j = 0; j < 8; ++j) v[j] = (bf16_t)src[(size_t)j * F_N];
    *(bf16x8*)(wb + (size_t)ch * CHBYTES + (kg << 9) + (hl << 4)) = v;
  } else {
    id -= 32768;
    const int Hg = id >> 8, cc = id & 255;
    const int ch = Hg >> 2, G = Hg & 3;
    bf16x8 v;
#pragma unroll
    for (int e = 0; e < 8; ++e) {
      const int hid = (ch << 5) + (e & 3) + ((((G >> 1) << 1) + (e >> 2)) << 3) + ((G & 1) << 2);
      v[e] = (bf16_t)W2[(size_t)hid * C_N + cc];
    }
    *(bf16x8*)(wb + (size_t)ch * CHBYTES + 16384 + (G << 12) + (cc << 4)) = v;
  }
}

// ---------------- stats pass 1: partial sum / sumsq over a T-slice ----------------
__global__ __launch_bounds__(256) void k_stats_partial(
    const float* __restrict__ x, float* __restrict__ psum, float* __restrict__ psq) {
  const int blk = blockIdx.x;
  const int b = blk / NSPLIT, s = blk % NSPLIT;
  const int tid = threadIdx.x;
  const int c4 = (tid & 63) << 2;
  const int tg = tid >> 6;
  const float* xb = x + ((size_t)b * T_N + (size_t)s * TSUB) * C_N;
  f32x4 sum = {0.f, 0.f, 0.f, 0.f};
  f32x4 sq  = {0.f, 0.f, 0.f, 0.f};
#pragma unroll 4
  for (int i = 0; i < TSUB / 4; ++i) {
    const int t = tg + (i << 2);
    f32x4 v = *(const f32x4*)(xb + (size_t)t * C_N + c4);
    sum += v;
    sq += v * v;
  }
  __shared__ f32x4 ls[256];
  __shared__ f32x4 lq[256];
  ls[tid] = sum; lq[tid] = sq;
  __syncthreads();
  if (tid < 64) {
    f32x4 S = ls[tid] + ls[tid + 64] + ls[tid + 128] + ls[tid + 192];
    f32x4 Q = lq[tid] + lq[tid + 64] + lq[tid + 128] + lq[tid + 192];
    *(f32x4*)(psum + (size_t)blk * C_N + c4) = S;
    *(f32x4*)(psq  + (size_t)blk * C_N + c4) = Q;
  }
}

// ---------------- stats pass 2: fused scale/shift (ddof=1) ----------------
__global__ __launch_bounds__(256) void k_stats_final(
    const float* __restrict__ psum, const float* __restrict__ psq,
    const float* __restrict__ gamma, const float* __restrict__ beta,
    float* __restrict__ As, float* __restrict__ Bs) {
  const int b = blockIdx.x, c = threadIdx.x;
  float S = 0.f, Q = 0.f;
#pragma unroll
  for (int s = 0; s < NSPLIT; ++s) {
    S += psum[(size_t)(b * NSPLIT + s) * C_N + c];
    Q += psq[(size_t)(b * NSPLIT + s) * C_N + c];
  }
  const float mu = S / (float)T_N;
  const float var = (Q - (float)T_N * mu * mu) / (float)(T_N - 1);
  const float a = rsqrtf(var + 1e-5f) * gamma[c];
  As[b * C_N + c] = a;
  Bs[b * C_N + c] = beta[c] - mu * a;
}

// ---------------- fused FFN: round-2 register structure (M=32/wave),
// 512-thread block (weights staged ONCE per CU), 3-slot ring staged 2 ahead,
// counted vmcnt(4) + raw s_barrier (no in-loop vmcnt(0) drain). ----------------
__global__ __launch_bounds__(512, 2) void k_ffn(
    const float* __restrict__ x, const float* __restrict__ As,
    const float* __restrict__ Bs, const float* __restrict__ b1,
    const float* __restrict__ b2, const bf16_t* __restrict__ wsW,
    float* __restrict__ out) {
  __shared__ __attribute__((aligned(128))) unsigned char lds[3 * CHBYTES + 4096];
  float* b1lds = (float*)(lds + 3 * CHBYTES);

  const int tid = threadIdx.x;            // 0..511, 8 waves
  const int lane = tid & 63;
  const int w = tid >> 6;
  const int l31 = lane & 31;
  const int g = lane >> 5;

  const int tok0 = blockIdx.x << 8;       // 256 tokens / block
  const int b = blockIdx.x >> 3;          // 8 blocks per batch row
  const int t0 = tok0 + (w << 5);         // this wave's 32 tokens

  const char* wsb = (const char*)wsW;

  // stage chunk 0 -> slot 0, chunk 1 -> slot 1 (4 x 16B per thread each)
#pragma unroll
  for (int j = 0; j < 4; ++j) {
    const int off = (j << 13) + (tid << 4);
    __builtin_amdgcn_global_load_lds((const GAS u32*)(wsb + off),
                                     (LAS u32*)(&lds[off]), 16, 0, 0);
  }
#pragma unroll
  for (int j = 0; j < 4; ++j) {
    const int off = (j << 13) + (tid << 4);
    __builtin_amdgcn_global_load_lds((const GAS u32*)(wsb + CHBYTES + off),
                                     (LAS u32*)(&lds[CHBYTES + off]), 16, 0, 0);
  }

  // b1 -> LDS (1024 f32, 2 per thread)
  {
    const int i2 = tid << 1;
    b1lds[i2] = b1[i2];
    b1lds[i2 + 1] = b1[i2 + 1];
  }

  // prologue: normalized h fragments (64 VGPR)
  bf16x8 hfrag[16];
  {
    const float* ar = As + b * C_N;
    const float* br = Bs + b * C_N;
    const float* xrow = x + (size_t)(t0 + l31) * C_N;
#pragma unroll
    for (int ks = 0; ks < 16; ++ks) {
      const int c0 = (ks << 4) + (g << 3);
      f32x8 xv = *(const f32x8*)(xrow + c0);
      f32x8 av = *(const f32x8*)(ar + c0);
      f32x8 bv = *(const f32x8*)(br + c0);
      f32x8 hv = xv * av + bv;
#pragma unroll
      for (int e = 0; e < 8; ++e) hfrag[ks][e] = (bf16_t)hv[e];
    }
  }

  f32x16 accO[8];
#pragma unroll
  for (int nb = 0; nb < 8; ++nb)
#pragma unroll
    for (int e = 0; e < 16; ++e) accO[nb][e] = 0.f;

  __syncthreads();   // full drain once: chunks 0/1 staged, b1 visible

  const unsigned char* bufA = lds;                 // compute (ch)
  const unsigned char* bufB = lds + CHBYTES;       // ready (ch+1)
  unsigned char* bufC = lds + 2 * CHBYTES;         // stage target (ch+2)
  const char* gnext = wsb + 2 * (size_t)CHBYTES;

#pragma unroll 1
  for (int ch = 0; ch < NCHUNK; ++ch) {
    // issue stage of ch+2 (4 loads/thread; stays in flight across the barrier)
    if (ch + 2 < NCHUNK) {
#pragma unroll
      for (int j = 0; j < 4; ++j) {
        const int off = (j << 13) + (tid << 4);
        __builtin_amdgcn_global_load_lds((const GAS u32*)(gnext + off),
                                         (LAS u32*)(bufC + off), 16, 0, 0);
      }
      gnext += CHBYTES;
    }
    const unsigned char* W1c = bufA;
    const unsigned char* W2c = bufA + 16384;

    // GEMM1 (swapped): D1[hid][token] = sum_k W1T[hid][k] * h[token][k]
    f32x16 D1;
#pragma unroll
    for (int e = 0; e < 16; ++e) D1[e] = 0.f;
#pragma unroll
    for (int ks = 0; ks < 16; ++ks) {
      const bf16x8 wf = *(const bf16x8*)(W1c + ((((ks << 1) + g) << 9) + (l31 << 4)));
      D1 = __builtin_amdgcn_mfma_f32_32x32x16_bf16(wf, hfrag[ks], D1, 0, 0, 0);
    }

    // bias + ReLU + cast: reg r holds hid = (r&3)+8*(r>>2)+4g  (b1 from LDS: lgkm only)
    f32x4 b1q[4];
#pragma unroll
    for (int q = 0; q < 4; ++q)
      b1q[q] = *(const f32x4*)(b1lds + (ch << 5) + (g << 2) + (q << 3));

    bf16x8 af[2];
#pragma unroll
    for (int r = 0; r < 16; ++r) {
      float v = D1[r] + b1q[r >> 2][r & 3];
      v = v > 0.f ? v : 0.f;
      af[r >> 3][r & 7] = (bf16_t)v;
    }

    // GEMM2: accO[nb] += a1 @ W2 (8 independent chains)
#pragma unroll
    for (int s = 0; s < 2; ++s) {
#pragma unroll
      for (int nb = 0; nb < 8; ++nb) {
        const bf16x8 wf2 = *(const bf16x8*)(W2c + ((((s << 1) + g) << 12) + (nb << 9) + (l31 << 4)));
        accO[nb] = __builtin_amdgcn_mfma_f32_32x32x16_bf16(af[s], wf2, accO[nb], 0, 0, 0);
      }
    }

    // counted wait: ch+1's 4 stage loads have landed; ch+2's 4 stay in flight.
    if (ch + 2 < NCHUNK) {
      asm volatile("s_waitcnt vmcnt(4)\n\ts_barrier" ::: "memory");
    } else if (ch + 1 < NCHUNK) {
      asm volatile("s_waitcnt vmcnt(0)\n\ts_barrier" ::: "memory");
    }

    const unsigned char* t = bufA; bufA = bufB; bufB = bufC; bufC = (unsigned char*)t;
  }

  // epilogue: out = accO + b2 + x   (token = t0 + 4g + rr + 8q, col = nb*32 + l31)
  {
    const float* xbase = x + (size_t)(t0 + (g << 2)) * C_N;
    float* obase = out + (size_t)(t0 + (g << 2)) * C_N;
#pragma unroll
    for (int nb = 0; nb < 8; ++nb) {
      const int c = (nb << 5) + l31;
      const float b2v = b2[c];
#pragma unroll
      for (int q = 0; q < 4; ++q) {
#pragma unroll
        for (int rr = 0; rr < 4; ++rr) {
          const size_t idx = (size_t)((q << 3) + rr) * C_N + c;
          obase[idx] = accO[nb][(q << 2) + rr] + b2v + xbase[idx];
        }
      }
    }
  }
}

extern "C" void kernel_launch(void* const* d_in, const int* in_sizes, int n_in,
                              void* d_out, int out_size, void* d_ws, size_t ws_size,
                              hipStream_t stream) {
  const float* x     = (const float*)d_in[0];
  const float* gamma = (const float*)d_in[1];
  const float* beta  = (const float*)d_in[2];
  const float* W1    = (const float*)d_in[3];
  const float* b1    = (const float*)d_in[4];
  const float* W2    = (const float*)d_in[5];
  const float* b2    = (const float*)d_in[6];
  float* out = (float*)d_out;

  char* ws = (char*)d_ws;
  bf16_t* wsW  = (bf16_t*)ws;                           // 1 MB
  float* psum  = (float*)(ws + (1024 << 10));           // 512 KB
  float* psq   = (float*)(ws + (1536 << 10));           // 512 KB
  float* As    = (float*)(ws + (2048 << 10));           // 32 KB
  float* Bs    = (float*)(ws + (2048 << 10) + (32 << 10));

  k_prep<<<256, 256, 0, stream>>>(W1, W2, wsW);
  k_stats_partial<<<B_N * NSPLIT, 256, 0, stream>>>(x, psum, psq);
  k_stats_final<<<B_N, 256, 0, stream>>>(psum, psq, gamma, beta, As, Bs);
  k_ffn<<<256, 512, 0, stream>>>(x, As, Bs, b1, b2, wsW, out);
}